// Round 4
// baseline (543.869 us; speedup 1.0000x reference)
//
#include <hip/hip_runtime.h>
#include <stdint.h>

#define N_ROWS 8192
#define M_COLS 128
#define F_DIM  1024
#define EPSF   1e-8f
// sim screen on fp8(16*f_norm), scales=1.0: sim_scaled = 256*sim, tau -> 204.8
#define TAU_SCALED 204.8f

typedef __attribute__((ext_vector_type(4))) float f32x4;
typedef int v8i __attribute__((ext_vector_type(8)));

__device__ __forceinline__ float wave_red_sum(float v) {
    #pragma unroll
    for (int o = 32; o > 0; o >>= 1) v += __shfl_down(v, o, 64);
    return v;
}

// async global->LDS, 16B per lane; LDS dest is wave-uniform base + lane*16
__device__ __forceinline__ void async16(const void* g, void* l) {
    __builtin_amdgcn_global_load_lds((const __attribute__((address_space(1))) void*)g,
                                     (__attribute__((address_space(3))) void*)l,
                                     16, 0, 0);
}

__device__ __forceinline__ float sigm(float x) { return 1.f / (1.f + __expf(-x)); }
__device__ __forceinline__ float bce1(float l, float y) {
    return fmaxf(l, 0.f) - l * y + log1pf(__expf(-fabsf(l)));
}

// ---- K1: y_pred, Lbasis, col sums, row sums (sq, Lsample), corr partial slice
__global__ __launch_bounds__(256) void k_pred(const float* __restrict__ logits,
    const float* __restrict__ ytrue, const float* __restrict__ cw,
    float* __restrict__ yp, float* __restrict__ sq,
    float* __restrict__ colp, float* __restrict__ colt,
    float* __restrict__ scal, float* __restrict__ cdp)
{
    __shared__ __align__(16) float Pl[32 * 128];
    __shared__ __align__(16) float Tl[32 * 128];
    __shared__ float redb[4], reds[4];
    int t = threadIdx.x, lane = t & 63;
    int rl = t >> 3, c0 = (t & 7) * 16;
    int r0 = blockIdx.x * 32;
    const float* lg = logits + (size_t)(r0 + rl) * 128 + c0;
    const float* yt = ytrue  + (size_t)(r0 + rl) * 128 + c0;
    float*       pw = yp     + (size_t)(r0 + rl) * 128 + c0;
    float bs = 0.f, sp = 0.f, ss = 0.f, st = 0.f;
    #pragma unroll
    for (int q = 0; q < 4; ++q) {
        float4 l4 = *(const float4*)(lg + q * 4);
        float4 y4 = *(const float4*)(yt + q * 4);
        float4 w4 = *(const float4*)(cw + c0 + q * 4);
        float4 p4;
        p4.x = sigm(l4.x); p4.y = sigm(l4.y); p4.z = sigm(l4.z); p4.w = sigm(l4.w);
        *(float4*)(pw + q * 4) = p4;
        *(float4*)&Pl[rl * 128 + c0 + q * 4] = p4;
        *(float4*)&Tl[rl * 128 + c0 + q * 4] = y4;
        bs += w4.x * bce1(l4.x, y4.x) + w4.y * bce1(l4.y, y4.y)
            + w4.z * bce1(l4.z, y4.z) + w4.w * bce1(l4.w, y4.w);
        sp += p4.x + p4.y + p4.z + p4.w;
        ss += p4.x * p4.x + p4.y * p4.y + p4.z * p4.z + p4.w * p4.w;
        st += y4.x + y4.y + y4.z + y4.w;
    }
    #pragma unroll
    for (int o = 1; o < 8; o <<= 1) {
        sp += __shfl_xor(sp, o, 8);
        ss += __shfl_xor(ss, o, 8);
        st += __shfl_xor(st, o, 8);
    }
    float ls = 0.f;
    if ((t & 7) == 0) {
        sq[r0 + rl] = ss;
        float e = fmaxf(1.f + st - sp, 0.f);   // E1=1, E2=1
        ls = e * e;
    }
    bs = wave_red_sum(bs);
    ls = wave_red_sum(ls);
    if (lane == 0) { redb[t >> 6] = bs; reds[t >> 6] = ls; }
    __syncthreads();
    if (t == 0) {
        atomicAdd(&scal[0], redb[0] + redb[1] + redb[2] + redb[3]);
        atomicAdd(&scal[2], reds[0] + reds[1] + reds[2] + reds[3]);
    }
    // column sums (Pl/Tl resident)
    if (t < 128) {
        float cp = 0.f;
        #pragma unroll 8
        for (int r = 0; r < 32; ++r) cp += Pl[r * 128 + t];
        atomicAdd(&colp[t], cp);
    } else {
        int c = t - 128;
        float ct = 0.f;
        #pragma unroll 8
        for (int r = 0; r < 32; ++r) ct += Tl[r * 128 + c];
        atomicAdd(&colt[c], ct);
    }
    // corr partial 8x8 tile per thread
    int tj = (t >> 4) * 8, tk = (t & 15) * 8;
    float acc[8][8];
    #pragma unroll
    for (int a = 0; a < 8; a++)
        #pragma unroll
        for (int b = 0; b < 8; b++) acc[a][b] = 0.f;
    for (int r = 0; r < 32; ++r) {
        float pj[8], pk[8], qj[8], qk[8];
        #pragma unroll
        for (int a = 0; a < 8; a++) { pj[a] = Pl[r * 128 + tj + a]; qj[a] = Tl[r * 128 + tj + a]; }
        #pragma unroll
        for (int b = 0; b < 8; b++) { pk[b] = Pl[r * 128 + tk + b]; qk[b] = Tl[r * 128 + tk + b]; }
        #pragma unroll
        for (int a = 0; a < 8; a++)
            #pragma unroll
            for (int b = 0; b < 8; b++)
                acc[a][b] += pj[a] * pk[b] - qj[a] * qk[b];
    }
    float* slice = cdp + (size_t)blockIdx.x * 16384;
    #pragma unroll
    for (int a = 0; a < 8; a++)
        #pragma unroll
        for (int b = 0; b < 8; b++)
            slice[(tj + a) * 128 + (tk + b)] = acc[a][b];
}

// ---- K2: f_norm -> fp8 e4m3 scaled by 16. One wave per row, no barriers.
__global__ __launch_bounds__(256) void k_norm(const float* __restrict__ feat,
    unsigned char* __restrict__ Fn8)
{
    int t = threadIdx.x, lane = t & 63, w = t >> 6;
    int row = blockIdx.x * 4 + w;
    const float4* f4 = (const float4*)(feat + (size_t)row * F_DIM);
    float4 v[4];
    float s = 0.f;
    #pragma unroll
    for (int it = 0; it < 4; ++it) {
        v[it] = f4[it * 64 + lane];
        s += v[it].x * v[it].x + v[it].y * v[it].y + v[it].z * v[it].z + v[it].w * v[it].w;
    }
    s = wave_red_sum(s);
    s = __shfl(s, 0, 64);
    float inv = 16.f / (sqrtf(s) + EPSF);
    int* o = (int*)(Fn8 + (size_t)row * F_DIM);
    #pragma unroll
    for (int it = 0; it < 4; ++it) {
        int r = 0;
        r = __builtin_amdgcn_cvt_pk_fp8_f32(v[it].x * inv, v[it].y * inv, r, false);
        r = __builtin_amdgcn_cvt_pk_fp8_f32(v[it].z * inv, v[it].w * inv, r, true);
        o[it * 64 + lane] = r;
    }
}

// ---- K3: reduce 256 corr slices, square, accumulate Lcol numerator -> scal[3]
__global__ __launch_bounds__(256) void k_colred(const float* __restrict__ cdp,
    float* __restrict__ scal)
{
    __shared__ float red[256];
    int t = threadIdx.x;
    int i = blockIdx.x * 256 + t;
    float s = 0.f;
    for (int sl = 0; sl < 256; ++sl) s += cdp[(size_t)sl * 16384 + i];
    float d = s * (1.f / 8192.f);
    red[t] = d * d;
    __syncthreads();
    for (int o = 128; o > 0; o >>= 1) { if (t < o) red[t] += red[t + o]; __syncthreads(); }
    if (t == 0) atomicAdd(&scal[3], red[0]);
}

// slow path: exact dist2 for an off-diagonal masked pair (never taken in practice)
__device__ __attribute__((noinline)) float pair_dist2(const float* yp, const float* sq,
                                                      int gi, int gj)
{
    const float* a = yp + (size_t)gi * 128;
    const float* b = yp + (size_t)gj * 128;
    float d = 0.f;
    for (int t = 0; t < 128; ++t) d += a[t] * b[t];
    return sq[gi] + sq[gj] - 2.f * d;
}

// ---- K4: scaled-sim screen via MX fp8 MFMA (K=128, scales=1.0), BK=128,
//          double-buffered LDS, proven conflict-free 128B-row XOR layout.
__global__ __launch_bounds__(256, 2) void k_sim(const unsigned char* __restrict__ Fn8,
    const float* __restrict__ yp, const float* __restrict__ sq, float* __restrict__ scal)
{
    __shared__ __align__(16) unsigned char As[2][16384];
    __shared__ __align__(16) unsigned char Bs[2][16384];
    // 2080 = 8 XCDs * 260: give each XCD a contiguous triangle range
    int b = blockIdx.x;
    int L = (b & 7) * 260 + (b >> 3);
    int bi = 0, rem = 64;
    while (L >= rem) { L -= rem; ++bi; --rem; }
    int bj = bi + L;
    int row0 = bi * 128, col0 = bj * 128;
    int t = threadIdx.x, lane = t & 63, w = t >> 6;
    int quad = lane >> 4, l15 = lane & 15;
    int wr = (w >> 1) * 64, wc = (w & 1) * 64;
    // staging map: thread t -> local row t>>3, physical chunk t&7 holds
    // logical k-chunk (t&7)^(row&7)
    int rloc = t >> 3;
    int coff = ((t & 7) ^ (rloc & 7)) << 4;
    const unsigned char* gA = Fn8 + (size_t)(row0 + rloc) * F_DIM + coff;
    const unsigned char* gB = Fn8 + (size_t)(col0 + rloc) * F_DIM + coff;
    // read map: lane needs logical chunks quad*2, quad*2+1 of its row
    int xk = l15 & 7;
    int cA0 = ((quad * 2) ^ xk) << 4, cA1 = ((quad * 2 + 1) ^ xk) << 4;

    f32x4 acc[4][4];
    #pragma unroll
    for (int i = 0; i < 4; i++)
        #pragma unroll
        for (int j2 = 0; j2 < 4; j2++) acc[i][j2] = (f32x4)0.f;

#define STAGE(K0, BUF) do {                                                        \
        _Pragma("unroll")                                                          \
        for (int R = 0; R < 4; ++R) {                                              \
            async16(gA + (size_t)R * 32 * F_DIM + (K0), &As[BUF][R * 4096 + t * 16]); \
            async16(gB + (size_t)R * 32 * F_DIM + (K0), &Bs[BUF][R * 4096 + t * 16]); \
        }                                                                          \
    } while (0)

    STAGE(0, 0);
    for (int it = 0; it < 8; ++it) {
        int cur = it & 1;
        __syncthreads();                       // drains stage(it) into buf cur
        if (it + 1 < 8) STAGE((it + 1) * 128, 1 - cur);
        v8i af[4], bf[4];
        #pragma unroll
        for (int i = 0; i < 4; ++i) {
            int rowa = (wr + i * 16 + l15) * 128;
            int4 lo = *(const int4*)&As[cur][rowa + cA0];
            int4 hi = *(const int4*)&As[cur][rowa + cA1];
            v8i a; a[0] = lo.x; a[1] = lo.y; a[2] = lo.z; a[3] = lo.w;
                   a[4] = hi.x; a[5] = hi.y; a[6] = hi.z; a[7] = hi.w;
            af[i] = a;
            int rowb = (wc + i * 16 + l15) * 128;
            lo = *(const int4*)&Bs[cur][rowb + cA0];
            hi = *(const int4*)&Bs[cur][rowb + cA1];
            v8i bb; bb[0] = lo.x; bb[1] = lo.y; bb[2] = lo.z; bb[3] = lo.w;
                    bb[4] = hi.x; bb[5] = hi.y; bb[6] = hi.z; bb[7] = hi.w;
            bf[i] = bb;
        }
        #pragma unroll
        for (int i = 0; i < 4; ++i)
            #pragma unroll
            for (int j2 = 0; j2 < 4; ++j2)
                acc[i][j2] = __builtin_amdgcn_mfma_scale_f32_16x16x128_f8f6f4(
                    af[i], bf[j2], acc[i][j2], 0, 0, 0, 0x7F7F7F7F, 0, 0x7F7F7F7F);
    }
#undef STAGE

    float local = 0.f;
    for (int i = 0; i < 4; i++)
        for (int j2 = 0; j2 < 4; j2++)
            for (int r = 0; r < 4; r++) {
                float v = acc[i][j2][r];
                if (v > TAU_SCALED) {
                    int gi = row0 + wr + i * 16 + quad * 4 + r;  // C layout: row = quad*4+reg
                    int gj = col0 + wc + j2 * 16 + l15;          //           col = lane&15
                    if (gi < gj) local += 2.f * pair_dist2(yp, sq, gi, gj);
                    // gi == gj: dist2 is exactly 0 — skip
                }
            }
    local = wave_red_sum(local);
    __syncthreads();                // all LDS reads done; reuse Bs for reduction
    if (lane == 0) ((float*)Bs[0])[w] = local;
    __syncthreads();
    if (t == 0) {
        float* r = (float*)Bs[0];
        atomicAdd(&scal[1], r[0] + r[1] + r[2] + r[3]);
    }
}

// ---- K5: assemble the 6 outputs (128 threads)
__global__ __launch_bounds__(128) void k_final(const float* __restrict__ colp,
    const float* __restrict__ colt, const float* __restrict__ scal,
    float* __restrict__ out)
{
    __shared__ float red2[2];
    int t = threadIdx.x;
    float Ej = colp[t] / 8192.f;
    float bp = colt[t];
    float bn = 8192.f - bp;
    float mint = 1.f + 0.2f * (bp / 8192.f);
    float moutt = 0.2f * ((8192.f - bp) / 8192.f);
    float pt = fmaxf(Ej - mint, 0.f);
    float nt = fmaxf(moutt - Ej, 0.f);
    float lc = bp * pt * pt + bn * nt * nt;
    lc = wave_red_sum(lc);
    if ((t & 63) == 0) red2[t >> 6] = lc;
    __syncthreads();
    if (t == 0) {
        float lclass = (red2[0] + red2[1]) / 8192.f;
        float lbasis = scal[0] / (8192.f * 128.f);
        float lstt = scal[1] / (8192.f * 8192.f);
        float lsample = scal[2] / 8192.f;
        float lcol = scal[3] / 16384.f;
        float ltotal = lbasis + 0.3f * lstt + 0.3f * lclass + 0.5f * lsample + 0.3f * lcol;
        out[0] = ltotal; out[1] = lbasis; out[2] = lstt;
        out[3] = lclass; out[4] = lsample; out[5] = lcol;
    }
}

extern "C" void kernel_launch(void* const* d_in, const int* in_sizes, int n_in,
                              void* d_out, int out_size, void* d_ws, size_t ws_size,
                              hipStream_t stream)
{
    const float* logits = (const float*)d_in[0];
    const float* ytrue  = (const float*)d_in[1];
    const float* feat   = (const float*)d_in[2];
    const float* cw     = (const float*)d_in[3];
    float* out = (float*)d_out;

    char* ws = (char*)d_ws;
    unsigned char* Fn8 = (unsigned char*)ws;                   // 8 MB fp8 f_norm (x16)
    float* yp   = (float*)(ws + (8u << 20));                   // 4 MB y_pred
    float* sq   = (float*)(ws + (12u << 20));                  // 32 KB row sums y_pred^2
    float* colp = (float*)(ws + (12u << 20) + 65536);          // 128 col sums pred
    float* colt = colp + 128;                                  // 128 col sums true
    float* scal = colp + 256;                                  // [0]=Lb [1]=Lstt [2]=Lsmp [3]=Lcol-num
    float* cdp  = (float*)(ws + (13u << 20));                  // 256 x 64 KB corr partials

    hipMemsetAsync(colp, 0, 2048, stream);

    k_pred<<<256, 256, 0, stream>>>(logits, ytrue, cw, yp, sq, colp, colt, scal, cdp);
    k_norm<<<2048, 256, 0, stream>>>(feat, Fn8);
    k_colred<<<64, 256, 0, stream>>>(cdp, scal);
    k_sim<<<2080, 256, 0, stream>>>(Fn8, yp, sq, scal);
    k_final<<<1, 128, 0, stream>>>(colp, colt, scal, out);
}

// Round 5
// 248.023 us; speedup vs baseline: 2.1928x; 2.1928x over previous
//
#include <hip/hip_runtime.h>
#include <stdint.h>

#define N_ROWS 8192
#define M_COLS 128
#define F_DIM  1024
#define EPSF   1e-8f
// sim screen on fp8(16*f_norm): sim_scaled = 256*sim, tau -> 204.8
#define TAU_SCALED 204.8f

typedef __attribute__((ext_vector_type(4))) float f32x4;
typedef __attribute__((ext_vector_type(2))) long long2v;

__device__ __forceinline__ float wave_red_sum(float v) {
    #pragma unroll
    for (int o = 32; o > 0; o >>= 1) v += __shfl_down(v, o, 64);
    return v;
}

// async global->LDS, 16B per lane; LDS dest is wave-uniform base + lane*16
__device__ __forceinline__ void async16(const void* g, void* l) {
    __builtin_amdgcn_global_load_lds((const __attribute__((address_space(1))) void*)g,
                                     (__attribute__((address_space(3))) void*)l,
                                     16, 0, 0);
}

__device__ __forceinline__ float sigm(float x) { return 1.f / (1.f + __expf(-x)); }
__device__ __forceinline__ float bce1(float l, float y) {
    return fmaxf(l, 0.f) - l * y + log1pf(__expf(-fabsf(l)));
}

// ---- K1 (merged): all 2048 blocks: f_norm->fp8 of 4 feature rows;
//      blocks < 256 additionally: y_pred, Lbasis, col sums, sq/Lsample, corr slice
__global__ __launch_bounds__(256) void k_prep(const float* __restrict__ logits,
    const float* __restrict__ ytrue, const float* __restrict__ cw,
    const float* __restrict__ feat, unsigned char* __restrict__ Fn8,
    float* __restrict__ yp, float* __restrict__ sq,
    float* __restrict__ colp, float* __restrict__ colt,
    float* __restrict__ scal, float* __restrict__ cdp)
{
    __shared__ __align__(16) float Pl[32 * 128];
    __shared__ __align__(16) float Tl[32 * 128];
    __shared__ float redb[4], reds[4];
    int t = threadIdx.x, lane = t & 63, w = t >> 6;

    // ---- norm part: one wave per feature row
    {
        int row = blockIdx.x * 4 + w;
        const float4* f4 = (const float4*)(feat + (size_t)row * F_DIM);
        float4 v[4];
        float s = 0.f;
        #pragma unroll
        for (int it = 0; it < 4; ++it) {
            v[it] = f4[it * 64 + lane];
            s += v[it].x * v[it].x + v[it].y * v[it].y + v[it].z * v[it].z + v[it].w * v[it].w;
        }
        s = wave_red_sum(s);
        s = __shfl(s, 0, 64);
        float inv = 16.f / (sqrtf(s) + EPSF);
        int* o = (int*)(Fn8 + (size_t)row * F_DIM);
        #pragma unroll
        for (int it = 0; it < 4; ++it) {
            int r = 0;
            r = __builtin_amdgcn_cvt_pk_fp8_f32(v[it].x * inv, v[it].y * inv, r, false);
            r = __builtin_amdgcn_cvt_pk_fp8_f32(v[it].z * inv, v[it].w * inv, r, true);
            o[it * 64 + lane] = r;
        }
    }

    if (blockIdx.x >= 256) return;

    // ---- pred part (uniform branch per block)
    int rl = t >> 3, c0 = (t & 7) * 16;
    int r0 = blockIdx.x * 32;
    const float* lg = logits + (size_t)(r0 + rl) * 128 + c0;
    const float* yt = ytrue  + (size_t)(r0 + rl) * 128 + c0;
    float*       pw = yp     + (size_t)(r0 + rl) * 128 + c0;
    float bs = 0.f, sp = 0.f, ss = 0.f, st = 0.f;
    #pragma unroll
    for (int q = 0; q < 4; ++q) {
        float4 l4 = *(const float4*)(lg + q * 4);
        float4 y4 = *(const float4*)(yt + q * 4);
        float4 w4 = *(const float4*)(cw + c0 + q * 4);
        float4 p4;
        p4.x = sigm(l4.x); p4.y = sigm(l4.y); p4.z = sigm(l4.z); p4.w = sigm(l4.w);
        *(float4*)(pw + q * 4) = p4;
        *(float4*)&Pl[rl * 128 + c0 + q * 4] = p4;
        *(float4*)&Tl[rl * 128 + c0 + q * 4] = y4;
        bs += w4.x * bce1(l4.x, y4.x) + w4.y * bce1(l4.y, y4.y)
            + w4.z * bce1(l4.z, y4.z) + w4.w * bce1(l4.w, y4.w);
        sp += p4.x + p4.y + p4.z + p4.w;
        ss += p4.x * p4.x + p4.y * p4.y + p4.z * p4.z + p4.w * p4.w;
        st += y4.x + y4.y + y4.z + y4.w;
    }
    #pragma unroll
    for (int o = 1; o < 8; o <<= 1) {
        sp += __shfl_xor(sp, o, 8);
        ss += __shfl_xor(ss, o, 8);
        st += __shfl_xor(st, o, 8);
    }
    float ls = 0.f;
    if ((t & 7) == 0) {
        sq[r0 + rl] = ss;
        float e = fmaxf(1.f + st - sp, 0.f);   // E1=1, E2=1
        ls = e * e;
    }
    bs = wave_red_sum(bs);
    ls = wave_red_sum(ls);
    if (lane == 0) { redb[w] = bs; reds[w] = ls; }
    __syncthreads();
    if (t == 0) {
        atomicAdd(&scal[0], redb[0] + redb[1] + redb[2] + redb[3]);
        atomicAdd(&scal[2], reds[0] + reds[1] + reds[2] + reds[3]);
    }
    if (t < 128) {
        float cp = 0.f;
        #pragma unroll 8
        for (int r = 0; r < 32; ++r) cp += Pl[r * 128 + t];
        atomicAdd(&colp[t], cp);
    } else {
        int c = t - 128;
        float ct = 0.f;
        #pragma unroll 8
        for (int r = 0; r < 32; ++r) ct += Tl[r * 128 + c];
        atomicAdd(&colt[c], ct);
    }
    // corr partial 8x8 tile per thread
    int tj = (t >> 4) * 8, tk = (t & 15) * 8;
    float acc[8][8];
    #pragma unroll
    for (int a = 0; a < 8; a++)
        #pragma unroll
        for (int b = 0; b < 8; b++) acc[a][b] = 0.f;
    for (int r = 0; r < 32; ++r) {
        float pj[8], pk[8], qj[8], qk[8];
        #pragma unroll
        for (int a = 0; a < 8; a++) { pj[a] = Pl[r * 128 + tj + a]; qj[a] = Tl[r * 128 + tj + a]; }
        #pragma unroll
        for (int b = 0; b < 8; b++) { pk[b] = Pl[r * 128 + tk + b]; qk[b] = Tl[r * 128 + tk + b]; }
        #pragma unroll
        for (int a = 0; a < 8; a++)
            #pragma unroll
            for (int b = 0; b < 8; b++)
                acc[a][b] += pj[a] * pk[b] - qj[a] * qk[b];
    }
    float* slice = cdp + (size_t)blockIdx.x * 16384;
    #pragma unroll
    for (int a = 0; a < 8; a++)
        #pragma unroll
        for (int b = 0; b < 8; b++)
            slice[(tj + a) * 128 + (tk + b)] = acc[a][b];
}

// slow path: exact dist2 for an off-diagonal masked pair (never taken in practice)
__device__ __attribute__((noinline)) float pair_dist2(const float* yp, const float* sq,
                                                      int gi, int gj)
{
    const float* a = yp + (size_t)gi * 128;
    const float* b = yp + (size_t)gj * 128;
    float d = 0.f;
    for (int t = 0; t < 128; ++t) d += a[t] * b[t];
    return sq[gi] + sq[gj] - 2.f * d;
}

// ---- K2: scaled-sim screen via fp8 MFMA, BK=64 dbuf, chunk-column-major LDS
//          (conflict-free: bank = f(row&7), 2 lanes/bank-group). Last 64 blocks
//          also reduce the corr slices; last-finished block assembles outputs.
__global__ __launch_bounds__(256, 4) void k_sim(const unsigned char* __restrict__ Fn8,
    const float* __restrict__ yp, const float* __restrict__ sq,
    const float* __restrict__ cdp, const float* __restrict__ colp,
    const float* __restrict__ colt, float* __restrict__ scal,
    float* __restrict__ out)
{
    __shared__ __align__(16) unsigned char As[2][8192];
    __shared__ __align__(16) unsigned char Bs[2][8192];
    __shared__ float fred[128];
    __shared__ int lastflag;
    int b = blockIdx.x;
    int t = threadIdx.x, lane = t & 63, w = t >> 6;

    // corr reduction on the last-issued 64 blocks
    if (b >= 2016) {
        int i = (b - 2016) * 256 + t;
        float s = 0.f;
        for (int sl = 0; sl < 256; ++sl) s += cdp[(size_t)sl * 16384 + i];
        float d = s * (1.f / 8192.f);
        float v = wave_red_sum(d * d);
        if (lane == 0) atomicAdd(&scal[3], v);
    }

    // 2080 = 8 XCDs * 260: contiguous triangle range per XCD
    int L = (b & 7) * 260 + (b >> 3);
    int bi = 0, rem = 64;
    while (L >= rem) { L -= rem; ++bi; --rem; }
    int bj = bi + L;
    int row0 = bi * 128, col0 = bj * 128;
    int quad = lane >> 4, l15 = lane & 15;
    int wr = (w >> 1) * 64, wc = (w & 1) * 64;
    // staging: thread t -> row t&63 (plus +64 batch), chunk t>>6.
    // LDS layout: region(row>>6)*4096 + chunk*1024 + (row&63)*16
    int sr = t & 63, sc = t >> 6;
    const unsigned char* gA = Fn8 + (size_t)(row0 + sr) * F_DIM + sc * 16;
    const unsigned char* gB = Fn8 + (size_t)(col0 + sr) * F_DIM + sc * 16;
    // read offsets: row = wr|wc + i*16 + l15, chunk = quad
    int aoff[4], boff[4];
    #pragma unroll
    for (int i = 0; i < 4; i++) {
        aoff[i] = (wr >> 6) * 4096 + quad * 1024 + (i * 16 + l15) * 16;
        boff[i] = (wc >> 6) * 4096 + quad * 1024 + (i * 16 + l15) * 16;
    }

    f32x4 acc[4][4];
    #pragma unroll
    for (int i = 0; i < 4; i++)
        #pragma unroll
        for (int j2 = 0; j2 < 4; j2++) acc[i][j2] = (f32x4)0.f;

#define STAGE(K0, BUF) do {                                         \
        async16(gA + (K0),               &As[BUF][t * 16]);         \
        async16(gA + (K0) + 64 * F_DIM,  &As[BUF][4096 + t * 16]);  \
        async16(gB + (K0),               &Bs[BUF][t * 16]);         \
        async16(gB + (K0) + 64 * F_DIM,  &Bs[BUF][4096 + t * 16]);  \
    } while (0)

    STAGE(0, 0);
    for (int it = 0; it < 16; ++it) {
        int cur = it & 1;
        __syncthreads();                       // drains stage(it) into buf cur
        if (it + 1 < 16) STAGE((it + 1) * 64, 1 - cur);
        long2v a2[4], b2[4];
        #pragma unroll
        for (int i = 0; i < 4; ++i) {
            a2[i] = *(const long2v*)&As[cur][aoff[i]];
            b2[i] = *(const long2v*)&Bs[cur][boff[i]];
        }
        #pragma unroll
        for (int i = 0; i < 4; ++i)
            #pragma unroll
            for (int j2 = 0; j2 < 4; ++j2)
                acc[i][j2] = __builtin_amdgcn_mfma_f32_16x16x32_fp8_fp8(
                    a2[i][0], b2[j2][0], acc[i][j2], 0, 0, 0);
        #pragma unroll
        for (int i = 0; i < 4; ++i)
            #pragma unroll
            for (int j2 = 0; j2 < 4; ++j2)
                acc[i][j2] = __builtin_amdgcn_mfma_f32_16x16x32_fp8_fp8(
                    a2[i][1], b2[j2][1], acc[i][j2], 0, 0, 0);
    }
#undef STAGE

    float local = 0.f;
    for (int i = 0; i < 4; i++)
        for (int j2 = 0; j2 < 4; j2++)
            for (int r = 0; r < 4; r++) {
                float v = acc[i][j2][r];
                if (v > TAU_SCALED) {
                    int gi = row0 + wr + i * 16 + quad * 4 + r;  // C layout: row = quad*4+reg
                    int gj = col0 + wc + j2 * 16 + l15;          //           col = lane&15
                    if (gi < gj) local += 2.f * pair_dist2(yp, sq, gi, gj);
                    // gi == gj: dist2 exactly 0 — skip
                }
            }
    local = wave_red_sum(local);
    if (lane == 0) fred[w] = local;
    __syncthreads();
    if (t == 0) {
        atomicAdd(&scal[1], fred[0] + fred[1] + fred[2] + fred[3]);
        __threadfence();
        unsigned old = atomicAdd((unsigned int*)&scal[4], 1u);
        lastflag = (old == 2079u);
    }
    __syncthreads();
    if (!lastflag) return;

    // ---- finale: this is the last block to finish
    __threadfence();
    if (t < 128) {
        float Ej = colp[t] / 8192.f;
        float bp = colt[t];
        float bn = 8192.f - bp;
        float mint = 1.f + 0.2f * (bp / 8192.f);
        float moutt = 0.2f * ((8192.f - bp) / 8192.f);
        float pt = fmaxf(Ej - mint, 0.f);
        float nt = fmaxf(moutt - Ej, 0.f);
        fred[t] = bp * pt * pt + bn * nt * nt;
    }
    __syncthreads();
    if (t < 64) {
        float v = fred[t] + fred[t + 64];
        v = wave_red_sum(v);
        if (t == 0) {
            float lclass = v / 8192.f;
            float lbasis = scal[0] / (8192.f * 128.f);
            float lstt = atomicAdd(&scal[1], 0.f) / (8192.f * 8192.f);
            float lsample = scal[2] / 8192.f;
            float lcol = atomicAdd(&scal[3], 0.f) / 16384.f;
            float ltotal = lbasis + 0.3f * lstt + 0.3f * lclass + 0.5f * lsample + 0.3f * lcol;
            out[0] = ltotal; out[1] = lbasis; out[2] = lstt;
            out[3] = lclass; out[4] = lsample; out[5] = lcol;
        }
    }
}

extern "C" void kernel_launch(void* const* d_in, const int* in_sizes, int n_in,
                              void* d_out, int out_size, void* d_ws, size_t ws_size,
                              hipStream_t stream)
{
    const float* logits = (const float*)d_in[0];
    const float* ytrue  = (const float*)d_in[1];
    const float* feat   = (const float*)d_in[2];
    const float* cw     = (const float*)d_in[3];
    float* out = (float*)d_out;

    char* ws = (char*)d_ws;
    unsigned char* Fn8 = (unsigned char*)ws;                   // 8 MB fp8 f_norm (x16)
    float* yp   = (float*)(ws + (8u << 20));                   // 4 MB y_pred
    float* sq   = (float*)(ws + (12u << 20));                  // 32 KB row sums y_pred^2
    float* colp = (float*)(ws + (12u << 20) + 65536);          // 128 col sums pred
    float* colt = colp + 128;                                  // 128 col sums true
    float* scal = colp + 256;                                  // [0]=Lb [1]=Lstt [2]=Lsmp [3]=Lcol [4]=ctr
    float* cdp  = (float*)(ws + (13u << 20));                  // 256 x 64 KB corr partials

    hipMemsetAsync(colp, 0, 2048, stream);

    k_prep<<<2048, 256, 0, stream>>>(logits, ytrue, cw, feat, Fn8, yp, sq,
                                     colp, colt, scal, cdp);
    k_sim<<<2080, 256, 0, stream>>>(Fn8, yp, sq, cdp, colp, colt, scal, out);
}

// Round 6
// 224.295 us; speedup vs baseline: 2.4248x; 1.1058x over previous
//
#include <hip/hip_runtime.h>
#include <stdint.h>

#define N_ROWS 8192
#define M_COLS 128
#define F_DIM  1024
#define EPSF   1e-8f
// sim screen on fp8(16*f_norm): sim_scaled = 256*sim, tau -> 204.8
#define TAU_SCALED 204.8f

typedef __attribute__((ext_vector_type(4))) float f32x4;
typedef __attribute__((ext_vector_type(2))) long long2v;

__device__ __forceinline__ float wave_red_sum(float v) {
    #pragma unroll
    for (int o = 32; o > 0; o >>= 1) v += __shfl_down(v, o, 64);
    return v;
}

// async global->LDS, 16B per lane; LDS dest is wave-uniform base + lane*16
__device__ __forceinline__ void async16(const void* g, void* l) {
    __builtin_amdgcn_global_load_lds((const __attribute__((address_space(1))) void*)g,
                                     (__attribute__((address_space(3))) void*)l,
                                     16, 0, 0);
}

__device__ __forceinline__ float sigm(float x) { return 1.f / (1.f + __expf(-x)); }
__device__ __forceinline__ float bce1(float l, float y) {
    return fmaxf(l, 0.f) - l * y + log1pf(__expf(-fabsf(l)));
}

// ---- K1 (merged): all 2048 blocks: f_norm->fp8 of 4 feature rows;
//      blocks < 256 additionally: y_pred, Lbasis, col sums, sq/Lsample, corr slice
__global__ __launch_bounds__(256) void k_prep(const float* __restrict__ logits,
    const float* __restrict__ ytrue, const float* __restrict__ cw,
    const float* __restrict__ feat, unsigned char* __restrict__ Fn8,
    float* __restrict__ yp, float* __restrict__ sq,
    float* __restrict__ colp, float* __restrict__ colt,
    float* __restrict__ scal, float* __restrict__ cdp)
{
    __shared__ __align__(16) float Pl[32 * 128];
    __shared__ __align__(16) float Tl[32 * 128];
    __shared__ float redb[4], reds[4];
    int t = threadIdx.x, lane = t & 63, w = t >> 6;

    // ---- norm part: one wave per feature row
    {
        int row = blockIdx.x * 4 + w;
        const float4* f4 = (const float4*)(feat + (size_t)row * F_DIM);
        float4 v[4];
        float s = 0.f;
        #pragma unroll
        for (int it = 0; it < 4; ++it) {
            v[it] = f4[it * 64 + lane];
            s += v[it].x * v[it].x + v[it].y * v[it].y + v[it].z * v[it].z + v[it].w * v[it].w;
        }
        s = wave_red_sum(s);
        s = __shfl(s, 0, 64);
        float inv = 16.f / (sqrtf(s) + EPSF);
        int* o = (int*)(Fn8 + (size_t)row * F_DIM);
        #pragma unroll
        for (int it = 0; it < 4; ++it) {
            int r = 0;
            r = __builtin_amdgcn_cvt_pk_fp8_f32(v[it].x * inv, v[it].y * inv, r, false);
            r = __builtin_amdgcn_cvt_pk_fp8_f32(v[it].z * inv, v[it].w * inv, r, true);
            o[it * 64 + lane] = r;
        }
    }

    if (blockIdx.x >= 256) return;

    // ---- pred part (uniform branch per block)
    int rl = t >> 3, c0 = (t & 7) * 16;
    int r0 = blockIdx.x * 32;
    const float* lg = logits + (size_t)(r0 + rl) * 128 + c0;
    const float* yt = ytrue  + (size_t)(r0 + rl) * 128 + c0;
    float*       pw = yp     + (size_t)(r0 + rl) * 128 + c0;
    float bs = 0.f, sp = 0.f, ss = 0.f, st = 0.f;
    #pragma unroll
    for (int q = 0; q < 4; ++q) {
        float4 l4 = *(const float4*)(lg + q * 4);
        float4 y4 = *(const float4*)(yt + q * 4);
        float4 w4 = *(const float4*)(cw + c0 + q * 4);
        float4 p4;
        p4.x = sigm(l4.x); p4.y = sigm(l4.y); p4.z = sigm(l4.z); p4.w = sigm(l4.w);
        *(float4*)(pw + q * 4) = p4;
        *(float4*)&Pl[rl * 128 + c0 + q * 4] = p4;
        *(float4*)&Tl[rl * 128 + c0 + q * 4] = y4;
        bs += w4.x * bce1(l4.x, y4.x) + w4.y * bce1(l4.y, y4.y)
            + w4.z * bce1(l4.z, y4.z) + w4.w * bce1(l4.w, y4.w);
        sp += p4.x + p4.y + p4.z + p4.w;
        ss += p4.x * p4.x + p4.y * p4.y + p4.z * p4.z + p4.w * p4.w;
        st += y4.x + y4.y + y4.z + y4.w;
    }
    #pragma unroll
    for (int o = 1; o < 8; o <<= 1) {
        sp += __shfl_xor(sp, o, 8);
        ss += __shfl_xor(ss, o, 8);
        st += __shfl_xor(st, o, 8);
    }
    float ls = 0.f;
    if ((t & 7) == 0) {
        sq[r0 + rl] = ss;
        float e = fmaxf(1.f + st - sp, 0.f);   // E1=1, E2=1
        ls = e * e;
    }
    bs = wave_red_sum(bs);
    ls = wave_red_sum(ls);
    if (lane == 0) { redb[w] = bs; reds[w] = ls; }
    __syncthreads();
    if (t == 0) {
        atomicAdd(&scal[0], redb[0] + redb[1] + redb[2] + redb[3]);
        atomicAdd(&scal[2], reds[0] + reds[1] + reds[2] + reds[3]);
    }
    if (t < 128) {
        float cp = 0.f;
        #pragma unroll 8
        for (int r = 0; r < 32; ++r) cp += Pl[r * 128 + t];
        atomicAdd(&colp[t], cp);
    } else {
        int c = t - 128;
        float ct = 0.f;
        #pragma unroll 8
        for (int r = 0; r < 32; ++r) ct += Tl[r * 128 + c];
        atomicAdd(&colt[c], ct);
    }
    // corr partial 8x8 tile per thread
    int tj = (t >> 4) * 8, tk = (t & 15) * 8;
    float acc[8][8];
    #pragma unroll
    for (int a = 0; a < 8; a++)
        #pragma unroll
        for (int b = 0; b < 8; b++) acc[a][b] = 0.f;
    for (int r = 0; r < 32; ++r) {
        float pj[8], pk[8], qj[8], qk[8];
        #pragma unroll
        for (int a = 0; a < 8; a++) { pj[a] = Pl[r * 128 + tj + a]; qj[a] = Tl[r * 128 + tj + a]; }
        #pragma unroll
        for (int b = 0; b < 8; b++) { pk[b] = Pl[r * 128 + tk + b]; qk[b] = Tl[r * 128 + tk + b]; }
        #pragma unroll
        for (int a = 0; a < 8; a++)
            #pragma unroll
            for (int b = 0; b < 8; b++)
                acc[a][b] += pj[a] * pk[b] - qj[a] * qk[b];
    }
    float* slice = cdp + (size_t)blockIdx.x * 16384;
    #pragma unroll
    for (int a = 0; a < 8; a++)
        #pragma unroll
        for (int b = 0; b < 8; b++)
            slice[(tj + a) * 128 + (tk + b)] = acc[a][b];
}

// slow path: exact dist2 for an off-diagonal masked pair (never taken in practice)
__device__ __attribute__((noinline)) float pair_dist2(const float* yp, const float* sq,
                                                      int gi, int gj)
{
    const float* a = yp + (size_t)gi * 128;
    const float* b = yp + (size_t)gj * 128;
    float d = 0.f;
    for (int t = 0; t < 128; ++t) d += a[t] * b[t];
    return sq[gi] + sq[gj] - 2.f * d;
}

// ---- K2: scaled-sim screen via fp8 MFMA, BK=128 dbuf.
// Staging: row-major XOR-permuted (thread t -> row t>>3, phys pos t&7 holds
// global chunk (t&7)^(row&7)) => 8 lanes = one contiguous 128B segment (coalesced).
// Read: row m, global chunk q at pos (q^(m&7))*16; row stride 128B => 2-way max (free).
__global__ __launch_bounds__(256, 2) void k_sim(const unsigned char* __restrict__ Fn8,
    const float* __restrict__ yp, const float* __restrict__ sq,
    const float* __restrict__ cdp, const float* __restrict__ colp,
    const float* __restrict__ colt, float* __restrict__ scal,
    float* __restrict__ out)
{
    __shared__ __align__(16) unsigned char As[2][16384];
    __shared__ __align__(16) unsigned char Bs[2][16384];
    __shared__ float fred[128];
    __shared__ int lastflag;
    int b = blockIdx.x;
    int t = threadIdx.x, lane = t & 63, w = t >> 6;

    // corr reduction folded into 64 blocks
    if (b >= 2016) {
        int i = (b - 2016) * 256 + t;
        float s = 0.f;
        for (int sl = 0; sl < 256; ++sl) s += cdp[(size_t)sl * 16384 + i];
        float d = s * (1.f / 8192.f);
        float v = wave_red_sum(d * d);
        if (lane == 0) atomicAdd(&scal[3], v);
    }

    // 2080 = 8 XCDs * 260: contiguous triangle range per XCD
    int L = (b & 7) * 260 + (b >> 3);
    int bi = 0, rem = 64;
    while (L >= rem) { L -= rem; ++bi; --rem; }
    int bj = bi + L;
    int row0 = bi * 128, col0 = bj * 128;
    int quad = lane >> 4, l15 = lane & 15;
    int wr = (w >> 1) * 64, wc = (w & 1) * 64;

    // staging map
    int srow = t >> 3;
    int g = (t & 7) ^ (srow & 7);
    const unsigned char* gA = Fn8 + (size_t)(row0 + srow) * F_DIM + g * 16;
    const unsigned char* gB = Fn8 + (size_t)(col0 + srow) * F_DIM + g * 16;

    // read offsets: pos for global chunk quad is (quad^xk)<<4; chunk quad+4 = ^64
    int xk = l15 & 7;
    int p0 = (quad ^ xk) << 4;
    int aoff[4], boff[4];
    #pragma unroll
    for (int i = 0; i < 4; i++) {
        aoff[i] = (wr + i * 16 + l15) * 128 + p0;
        boff[i] = (wc + i * 16 + l15) * 128 + p0;
    }

    f32x4 acc[4][4];
    #pragma unroll
    for (int i = 0; i < 4; i++)
        #pragma unroll
        for (int j2 = 0; j2 < 4; j2++) acc[i][j2] = (f32x4)0.f;

#define STAGE(K0, BUF) do {                                                          \
        _Pragma("unroll")                                                            \
        for (int R = 0; R < 4; ++R) {                                                \
            async16(gA + (size_t)R * 32 * F_DIM + (K0), &As[BUF][R * 4096 + t * 16]); \
            async16(gB + (size_t)R * 32 * F_DIM + (K0), &Bs[BUF][R * 4096 + t * 16]); \
        }                                                                            \
    } while (0)

    STAGE(0, 0);
    for (int it = 0; it < 8; ++it) {
        int cur = it & 1;
        __syncthreads();                       // drains stage(it) into buf cur
        if (it + 1 < 8) STAGE((it + 1) * 128, 1 - cur);
        #pragma unroll
        for (int half = 0; half < 2; ++half) {
            int ho = half << 6;                // chunk quad+4 lives at pos^64
            long2v a2[4], b2[4];
            #pragma unroll
            for (int i = 0; i < 4; ++i) {
                a2[i] = *(const long2v*)&As[cur][aoff[i] ^ ho];
                b2[i] = *(const long2v*)&Bs[cur][boff[i] ^ ho];
            }
            #pragma unroll
            for (int i = 0; i < 4; ++i)
                #pragma unroll
                for (int j2 = 0; j2 < 4; ++j2)
                    acc[i][j2] = __builtin_amdgcn_mfma_f32_16x16x32_fp8_fp8(
                        a2[i][0], b2[j2][0], acc[i][j2], 0, 0, 0);
            #pragma unroll
            for (int i = 0; i < 4; ++i)
                #pragma unroll
                for (int j2 = 0; j2 < 4; ++j2)
                    acc[i][j2] = __builtin_amdgcn_mfma_f32_16x16x32_fp8_fp8(
                        a2[i][1], b2[j2][1], acc[i][j2], 0, 0, 0);
        }
    }
#undef STAGE

    float local = 0.f;
    for (int i = 0; i < 4; i++)
        for (int j2 = 0; j2 < 4; j2++)
            for (int r = 0; r < 4; r++) {
                float v = acc[i][j2][r];
                if (v > TAU_SCALED) {
                    int gi = row0 + wr + i * 16 + quad * 4 + r;  // C layout: row = quad*4+reg
                    int gj = col0 + wc + j2 * 16 + l15;          //           col = lane&15
                    if (gi < gj) local += 2.f * pair_dist2(yp, sq, gi, gj);
                    // gi == gj: dist2 exactly 0 — skip
                }
            }
    local = wave_red_sum(local);
    if (lane == 0) fred[w] = local;
    __syncthreads();
    if (t == 0) {
        atomicAdd(&scal[1], fred[0] + fred[1] + fred[2] + fred[3]);
        __threadfence();
        unsigned old = atomicAdd((unsigned int*)&scal[4], 1u);
        lastflag = (old == 2079u);
    }
    __syncthreads();
    if (!lastflag) return;

    // ---- finale: last block to finish assembles the outputs
    __threadfence();
    if (t < 128) {
        float Ej = colp[t] / 8192.f;
        float bp = colt[t];
        float bn = 8192.f - bp;
        float mint = 1.f + 0.2f * (bp / 8192.f);
        float moutt = 0.2f * ((8192.f - bp) / 8192.f);
        float pt = fmaxf(Ej - mint, 0.f);
        float nt = fmaxf(moutt - Ej, 0.f);
        fred[t] = bp * pt * pt + bn * nt * nt;
    }
    __syncthreads();
    if (t < 64) {
        float v = fred[t] + fred[t + 64];
        v = wave_red_sum(v);
        if (t == 0) {
            float lclass = v / 8192.f;
            float lbasis = scal[0] / (8192.f * 128.f);
            float lstt = atomicAdd(&scal[1], 0.f) / (8192.f * 8192.f);
            float lsample = scal[2] / 8192.f;
            float lcol = atomicAdd(&scal[3], 0.f) / 16384.f;
            float ltotal = lbasis + 0.3f * lstt + 0.3f * lclass + 0.5f * lsample + 0.3f * lcol;
            out[0] = ltotal; out[1] = lbasis; out[2] = lstt;
            out[3] = lclass; out[4] = lsample; out[5] = lcol;
        }
    }
}

extern "C" void kernel_launch(void* const* d_in, const int* in_sizes, int n_in,
                              void* d_out, int out_size, void* d_ws, size_t ws_size,
                              hipStream_t stream)
{
    const float* logits = (const float*)d_in[0];
    const float* ytrue  = (const float*)d_in[1];
    const float* feat   = (const float*)d_in[2];
    const float* cw     = (const float*)d_in[3];
    float* out = (float*)d_out;

    char* ws = (char*)d_ws;
    unsigned char* Fn8 = (unsigned char*)ws;                   // 8 MB fp8 f_norm (x16)
    float* yp   = (float*)(ws + (8u << 20));                   // 4 MB y_pred
    float* sq   = (float*)(ws + (12u << 20));                  // 32 KB row sums y_pred^2
    float* colp = (float*)(ws + (12u << 20) + 65536);          // 128 col sums pred
    float* colt = colp + 128;                                  // 128 col sums true
    float* scal = colp + 256;                                  // [0]=Lb [1]=Lstt [2]=Lsmp [3]=Lcol [4]=ctr
    float* cdp  = (float*)(ws + (13u << 20));                  // 256 x 64 KB corr partials

    hipMemsetAsync(colp, 0, 2048, stream);

    k_prep<<<2048, 256, 0, stream>>>(logits, ytrue, cw, feat, Fn8, yp, sq,
                                     colp, colt, scal, cdp);
    k_sim<<<2080, 256, 0, stream>>>(Fn8, yp, sq, cdp, colp, colt, scal, out);
}

// Round 7
// 220.607 us; speedup vs baseline: 2.4653x; 1.0167x over previous
//
#include <hip/hip_runtime.h>
#include <stdint.h>

#define N_ROWS 8192
#define M_COLS 128
#define F_DIM  1024
#define EPSF   1e-8f
// sim screen on fp8(16*f_norm): sim_scaled = 256*sim, tau -> 204.8
#define TAU_SCALED 204.8f

typedef __attribute__((ext_vector_type(4))) float f32x4;

__device__ __forceinline__ float wave_red_sum(float v) {
    #pragma unroll
    for (int o = 32; o > 0; o >>= 1) v += __shfl_down(v, o, 64);
    return v;
}

// async global->LDS, 16B per lane; LDS dest is wave-uniform base + lane*16
__device__ __forceinline__ void async16(const void* g, void* l) {
    __builtin_amdgcn_global_load_lds((const __attribute__((address_space(1))) void*)g,
                                     (__attribute__((address_space(3))) void*)l,
                                     16, 0, 0);
}

__device__ __forceinline__ float sigm(float x) { return 1.f / (1.f + __expf(-x)); }
__device__ __forceinline__ float bce1(float l, float y) {
    return fmaxf(l, 0.f) - l * y + log1pf(__expf(-fabsf(l)));
}

// ---- K1 (merged): all 2048 blocks: f_norm->fp8 of 4 feature rows;
//      blocks < 256 additionally: y_pred, Lbasis, col sums, sq/Lsample, corr slice
__global__ __launch_bounds__(256) void k_prep(const float* __restrict__ logits,
    const float* __restrict__ ytrue, const float* __restrict__ cw,
    const float* __restrict__ feat, unsigned char* __restrict__ Fn8,
    float* __restrict__ yp, float* __restrict__ sq,
    float* __restrict__ colp, float* __restrict__ colt,
    float* __restrict__ scal, float* __restrict__ cdp)
{
    __shared__ __align__(16) float Pl[32 * 128];
    __shared__ __align__(16) float Tl[32 * 128];
    __shared__ float redb[4], reds[4];
    int t = threadIdx.x, lane = t & 63, w = t >> 6;

    // ---- norm part: one wave per feature row
    {
        int row = blockIdx.x * 4 + w;
        const float4* f4 = (const float4*)(feat + (size_t)row * F_DIM);
        float4 v[4];
        float s = 0.f;
        #pragma unroll
        for (int it = 0; it < 4; ++it) {
            v[it] = f4[it * 64 + lane];
            s += v[it].x * v[it].x + v[it].y * v[it].y + v[it].z * v[it].z + v[it].w * v[it].w;
        }
        s = wave_red_sum(s);
        s = __shfl(s, 0, 64);
        float inv = 16.f / (sqrtf(s) + EPSF);
        int* o = (int*)(Fn8 + (size_t)row * F_DIM);
        #pragma unroll
        for (int it = 0; it < 4; ++it) {
            int r = 0;
            r = __builtin_amdgcn_cvt_pk_fp8_f32(v[it].x * inv, v[it].y * inv, r, false);
            r = __builtin_amdgcn_cvt_pk_fp8_f32(v[it].z * inv, v[it].w * inv, r, true);
            o[it * 64 + lane] = r;
        }
    }

    if (blockIdx.x >= 256) return;

    // ---- pred part (uniform branch per block)
    int rl = t >> 3, c0 = (t & 7) * 16;
    int r0 = blockIdx.x * 32;
    const float* lg = logits + (size_t)(r0 + rl) * 128 + c0;
    const float* yt = ytrue  + (size_t)(r0 + rl) * 128 + c0;
    float*       pw = yp     + (size_t)(r0 + rl) * 128 + c0;
    float bs = 0.f, sp = 0.f, ss = 0.f, st = 0.f;
    #pragma unroll
    for (int q = 0; q < 4; ++q) {
        float4 l4 = *(const float4*)(lg + q * 4);
        float4 y4 = *(const float4*)(yt + q * 4);
        float4 w4 = *(const float4*)(cw + c0 + q * 4);
        float4 p4;
        p4.x = sigm(l4.x); p4.y = sigm(l4.y); p4.z = sigm(l4.z); p4.w = sigm(l4.w);
        *(float4*)(pw + q * 4) = p4;
        *(float4*)&Pl[rl * 128 + c0 + q * 4] = p4;
        *(float4*)&Tl[rl * 128 + c0 + q * 4] = y4;
        bs += w4.x * bce1(l4.x, y4.x) + w4.y * bce1(l4.y, y4.y)
            + w4.z * bce1(l4.z, y4.z) + w4.w * bce1(l4.w, y4.w);
        sp += p4.x + p4.y + p4.z + p4.w;
        ss += p4.x * p4.x + p4.y * p4.y + p4.z * p4.z + p4.w * p4.w;
        st += y4.x + y4.y + y4.z + y4.w;
    }
    #pragma unroll
    for (int o = 1; o < 8; o <<= 1) {
        sp += __shfl_xor(sp, o, 8);
        ss += __shfl_xor(ss, o, 8);
        st += __shfl_xor(st, o, 8);
    }
    float ls = 0.f;
    if ((t & 7) == 0) {
        sq[r0 + rl] = ss;
        float e = fmaxf(1.f + st - sp, 0.f);   // E1=1, E2=1
        ls = e * e;
    }
    bs = wave_red_sum(bs);
    ls = wave_red_sum(ls);
    if (lane == 0) { redb[w] = bs; reds[w] = ls; }
    __syncthreads();
    if (t == 0) {
        atomicAdd(&scal[0], redb[0] + redb[1] + redb[2] + redb[3]);
        atomicAdd(&scal[2], reds[0] + reds[1] + reds[2] + reds[3]);
    }
    if (t < 128) {
        float cp = 0.f;
        #pragma unroll 8
        for (int r = 0; r < 32; ++r) cp += Pl[r * 128 + t];
        atomicAdd(&colp[t], cp);
    } else {
        int c = t - 128;
        float ct = 0.f;
        #pragma unroll 8
        for (int r = 0; r < 32; ++r) ct += Tl[r * 128 + c];
        atomicAdd(&colt[c], ct);
    }
    // corr partial 8x8 tile per thread
    int tj = (t >> 4) * 8, tk = (t & 15) * 8;
    float acc[8][8];
    #pragma unroll
    for (int a = 0; a < 8; a++)
        #pragma unroll
        for (int b = 0; b < 8; b++) acc[a][b] = 0.f;
    for (int r = 0; r < 32; ++r) {
        float pj[8], pk[8], qj[8], qk[8];
        #pragma unroll
        for (int a = 0; a < 8; a++) { pj[a] = Pl[r * 128 + tj + a]; qj[a] = Tl[r * 128 + tj + a]; }
        #pragma unroll
        for (int b = 0; b < 8; b++) { pk[b] = Pl[r * 128 + tk + b]; qk[b] = Tl[r * 128 + tk + b]; }
        #pragma unroll
        for (int a = 0; a < 8; a++)
            #pragma unroll
            for (int b = 0; b < 8; b++)
                acc[a][b] += pj[a] * pk[b] - qj[a] * qk[b];
    }
    float* slice = cdp + (size_t)blockIdx.x * 16384;
    #pragma unroll
    for (int a = 0; a < 8; a++)
        #pragma unroll
        for (int b = 0; b < 8; b++)
            slice[(tj + a) * 128 + (tk + b)] = acc[a][b];
}

// slow path: exact dist2 for an off-diagonal masked pair (never taken in practice)
__device__ __attribute__((noinline)) float pair_dist2(const float* yp, const float* sq,
                                                      int gi, int gj)
{
    const float* a = yp + (size_t)gi * 128;
    const float* b = yp + (size_t)gj * 128;
    float d = 0.f;
    for (int t = 0; t < 128; ++t) d += a[t] * b[t];
    return sq[gi] + sq[gj] - 2.f * d;
}

// ---- K2: scaled-sim screen via fp8 MFMA, BK=64, 32KB dbuf -> 4 blocks/CU.
// LDS: paired-row layout. Logical (row, chunk c in 0..3, 16B) stored at
//   line = row>>1 (128B lines), slot = (c | ((row&1)<<2)) ^ (line&7).
// Staging thread t -> dest t*16 = (line t>>3, slot t&7); inverse gives its
//   global (row, chunk). 8 lanes cover rows {2l,2l+1} x 64B contiguous.
// Read (quad,l15), k-step kk: c = kk*2+(quad>>1), b64 at (quad&1)*8 within
//   slot -> bank = f(slot) only; each slot hit exactly 2x per quad => free.
__global__ __launch_bounds__(256, 4) void k_sim(const unsigned char* __restrict__ Fn8,
    const float* __restrict__ yp, const float* __restrict__ sq,
    const float* __restrict__ cdp, const float* __restrict__ colp,
    const float* __restrict__ colt, float* __restrict__ scal,
    float* __restrict__ out)
{
    __shared__ __align__(16) unsigned char As[2][8192];
    __shared__ __align__(16) unsigned char Bs[2][8192];
    __shared__ float fred[128];
    __shared__ int lastflag;
    int b = blockIdx.x;
    int t = threadIdx.x, lane = t & 63, w = t >> 6;

    // corr reduction folded into 64 blocks
    if (b >= 2016) {
        int i = (b - 2016) * 256 + t;
        float s = 0.f;
        for (int sl = 0; sl < 256; ++sl) s += cdp[(size_t)sl * 16384 + i];
        float d = s * (1.f / 8192.f);
        float v = wave_red_sum(d * d);
        if (lane == 0) atomicAdd(&scal[3], v);
    }

    // 2080 = 8 XCDs * 260: contiguous triangle range per XCD
    int L = (b & 7) * 260 + (b >> 3);
    int bi = 0, rem = 64;
    while (L >= rem) { L -= rem; ++bi; --rem; }
    int bj = bi + L;
    int row0 = bi * 128, col0 = bj * 128;
    int quad = lane >> 4, l15 = lane & 15;
    int wr = (w >> 1) * 64, wc = (w & 1) * 64;

    // staging map: t -> line l = t>>3, slot s = t&7; u = s^(l&7)
    {
    }
    int sl_ = t & 7, ln_ = t >> 3;
    int u_ = sl_ ^ (ln_ & 7);
    int srow = ln_ * 2 + (u_ >> 2);      // 0..63
    int schunk = u_ & 3;
    const unsigned char* gA = Fn8 + (size_t)(row0 + srow) * F_DIM + schunk * 16;
    const unsigned char* gB = Fn8 + (size_t)(col0 + srow) * F_DIM + schunk * 16;

    // read offsets: h = l15>>1, pp = (l15&1)<<2
    int h = l15 >> 1, pp = (l15 & 1) << 2, q1 = (quad & 1) * 8, qh = quad >> 1;
    // per kk: slot = ((kk*2 + qh) | pp) ^ h ; off = h*128 + slot*16 + q1
    int off0 = h * 128 + ((((0 * 2 + qh) | pp) ^ h) << 4) + q1;
    int off1 = h * 128 + ((((1 * 2 + qh) | pp) ^ h) << 4) + q1;

    f32x4 acc[4][4];
    #pragma unroll
    for (int i = 0; i < 4; i++)
        #pragma unroll
        for (int j2 = 0; j2 < 4; j2++) acc[i][j2] = (f32x4)0.f;

#define STAGE(K0, BUF) do {                                          \
        async16(gA + (K0),              &As[BUF][t * 16]);           \
        async16(gA + (K0) + 64 * F_DIM, &As[BUF][4096 + t * 16]);    \
        async16(gB + (K0),              &Bs[BUF][t * 16]);           \
        async16(gB + (K0) + 64 * F_DIM, &Bs[BUF][4096 + t * 16]);    \
    } while (0)

    STAGE(0, 0);
    for (int it = 0; it < 16; ++it) {
        int cur = it & 1;
        __syncthreads();                       // drains stage(it) into buf cur
        if (it + 1 < 16) STAGE((it + 1) * 64, 1 - cur);
        long a0[4], b0[4], a1[4], b1[4];
        #pragma unroll
        for (int i = 0; i < 4; ++i) {
            int basA = wr * 64 + i * 1024;     // row block base (region+rows)
            int basB = wc * 64 + i * 1024;
            a0[i] = *(const long*)&As[cur][basA + off0];
            a1[i] = *(const long*)&As[cur][basA + off1];
            b0[i] = *(const long*)&Bs[cur][basB + off0];
            b1[i] = *(const long*)&Bs[cur][basB + off1];
        }
        #pragma unroll
        for (int i = 0; i < 4; ++i)
            #pragma unroll
            for (int j2 = 0; j2 < 4; ++j2)
                acc[i][j2] = __builtin_amdgcn_mfma_f32_16x16x32_fp8_fp8(
                    a0[i], b0[j2], acc[i][j2], 0, 0, 0);
        #pragma unroll
        for (int i = 0; i < 4; ++i)
            #pragma unroll
            for (int j2 = 0; j2 < 4; ++j2)
                acc[i][j2] = __builtin_amdgcn_mfma_f32_16x16x32_fp8_fp8(
                    a1[i], b1[j2], acc[i][j2], 0, 0, 0);
    }
#undef STAGE

    float local = 0.f;
    for (int i = 0; i < 4; i++)
        for (int j2 = 0; j2 < 4; j2++)
            for (int r = 0; r < 4; r++) {
                float v = acc[i][j2][r];
                if (v > TAU_SCALED) {
                    int gi = row0 + wr + i * 16 + quad * 4 + r;  // C layout: row = quad*4+reg
                    int gj = col0 + wc + j2 * 16 + l15;          //           col = lane&15
                    if (gi < gj) local += 2.f * pair_dist2(yp, sq, gi, gj);
                    // gi == gj: dist2 exactly 0 — skip
                }
            }
    local = wave_red_sum(local);
    if (lane == 0) fred[w] = local;
    __syncthreads();
    if (t == 0) {
        atomicAdd(&scal[1], fred[0] + fred[1] + fred[2] + fred[3]);
        __threadfence();
        unsigned old = atomicAdd((unsigned int*)&scal[4], 1u);
        lastflag = (old == 2079u);
    }
    __syncthreads();
    if (!lastflag) return;

    // ---- finale: last block to finish assembles the outputs
    __threadfence();
    if (t < 128) {
        float Ej = colp[t] / 8192.f;
        float bp = colt[t];
        float bn = 8192.f - bp;
        float mint = 1.f + 0.2f * (bp / 8192.f);
        float moutt = 0.2f * ((8192.f - bp) / 8192.f);
        float pt = fmaxf(Ej - mint, 0.f);
        float nt = fmaxf(moutt - Ej, 0.f);
        fred[t] = bp * pt * pt + bn * nt * nt;
    }
    __syncthreads();
    if (t < 64) {
        float v = fred[t] + fred[t + 64];
        v = wave_red_sum(v);
        if (t == 0) {
            float lclass = v / 8192.f;
            float lbasis = scal[0] / (8192.f * 128.f);
            float lstt = atomicAdd(&scal[1], 0.f) / (8192.f * 8192.f);
            float lsample = scal[2] / 8192.f;
            float lcol = atomicAdd(&scal[3], 0.f) / 16384.f;
            float ltotal = lbasis + 0.3f * lstt + 0.3f * lclass + 0.5f * lsample + 0.3f * lcol;
            out[0] = ltotal; out[1] = lbasis; out[2] = lstt;
            out[3] = lclass; out[4] = lsample; out[5] = lcol;
        }
    }
}

extern "C" void kernel_launch(void* const* d_in, const int* in_sizes, int n_in,
                              void* d_out, int out_size, void* d_ws, size_t ws_size,
                              hipStream_t stream)
{
    const float* logits = (const float*)d_in[0];
    const float* ytrue  = (const float*)d_in[1];
    const float* feat   = (const float*)d_in[2];
    const float* cw     = (const float*)d_in[3];
    float* out = (float*)d_out;

    char* ws = (char*)d_ws;
    unsigned char* Fn8 = (unsigned char*)ws;                   // 8 MB fp8 f_norm (x16)
    float* yp   = (float*)(ws + (8u << 20));                   // 4 MB y_pred
    float* sq   = (float*)(ws + (12u << 20));                  // 32 KB row sums y_pred^2
    float* colp = (float*)(ws + (12u << 20) + 65536);          // 128 col sums pred
    float* colt = colp + 128;                                  // 128 col sums true
    float* scal = colp + 256;                                  // [0]=Lb [1]=Lstt [2]=Lsmp [3]=Lcol [4]=ctr
    float* cdp  = (float*)(ws + (13u << 20));                  // 256 x 64 KB corr partials

    hipMemsetAsync(colp, 0, 2048, stream);

    k_prep<<<2048, 256, 0, stream>>>(logits, ytrue, cw, feat, Fn8, yp, sq,
                                     colp, colt, scal, cdp);
    k_sim<<<2080, 256, 0, stream>>>(Fn8, yp, sq, cdp, colp, colt, scal, out);
}

// Round 8
// 186.005 us; speedup vs baseline: 2.9240x; 1.1860x over previous
//
#include <hip/hip_runtime.h>
#include <stdint.h>

#define N_ROWS 8192
#define M_COLS 128
#define F_DIM  1024
#define EPSF   1e-8f
// sim screen on fp8(16*f_norm): sim_scaled = 256*sim, tau -> 204.8
#define TAU_SCALED 204.8f
#define NTILE 1056          // 256x128 upper-triangle tiles: sum_{i<32}(64-2i)

typedef __attribute__((ext_vector_type(4))) float f32x4;

__device__ __forceinline__ float wave_red_sum(float v) {
    #pragma unroll
    for (int o = 32; o > 0; o >>= 1) v += __shfl_down(v, o, 64);
    return v;
}

// async global->LDS, 16B per lane; LDS dest is wave-uniform base + lane*16
__device__ __forceinline__ void async16(const void* g, void* l) {
    __builtin_amdgcn_global_load_lds((const __attribute__((address_space(1))) void*)g,
                                     (__attribute__((address_space(3))) void*)l,
                                     16, 0, 0);
}

__device__ __forceinline__ float sigm(float x) { return 1.f / (1.f + __expf(-x)); }
__device__ __forceinline__ float bce1(float l, float y) {
    return fmaxf(l, 0.f) - l * y + log1pf(__expf(-fabsf(l)));
}

// ---- K1 (merged): all 2048 blocks: f_norm->fp8 of 4 feature rows;
//      blocks < 256 additionally: y_pred, Lbasis, col sums, sq/Lsample, corr slice
__global__ __launch_bounds__(256) void k_prep(const float* __restrict__ logits,
    const float* __restrict__ ytrue, const float* __restrict__ cw,
    const float* __restrict__ feat, unsigned char* __restrict__ Fn8,
    float* __restrict__ yp, float* __restrict__ sq,
    float* __restrict__ colp, float* __restrict__ colt,
    float* __restrict__ scal, float* __restrict__ cdp)
{
    __shared__ __align__(16) float Pl[32 * 128];
    __shared__ __align__(16) float Tl[32 * 128];
    __shared__ float redb[4], reds[4];
    int t = threadIdx.x, lane = t & 63, w = t >> 6;

    // ---- norm part: one wave per feature row
    {
        int row = blockIdx.x * 4 + w;
        const float4* f4 = (const float4*)(feat + (size_t)row * F_DIM);
        float4 v[4];
        float s = 0.f;
        #pragma unroll
        for (int it = 0; it < 4; ++it) {
            v[it] = f4[it * 64 + lane];
            s += v[it].x * v[it].x + v[it].y * v[it].y + v[it].z * v[it].z + v[it].w * v[it].w;
        }
        s = wave_red_sum(s);
        s = __shfl(s, 0, 64);
        float inv = 16.f / (sqrtf(s) + EPSF);
        int* o = (int*)(Fn8 + (size_t)row * F_DIM);
        #pragma unroll
        for (int it = 0; it < 4; ++it) {
            int r = 0;
            r = __builtin_amdgcn_cvt_pk_fp8_f32(v[it].x * inv, v[it].y * inv, r, false);
            r = __builtin_amdgcn_cvt_pk_fp8_f32(v[it].z * inv, v[it].w * inv, r, true);
            o[it * 64 + lane] = r;
        }
    }

    if (blockIdx.x >= 256) return;

    // ---- pred part (uniform branch per block)
    int rl = t >> 3, c0 = (t & 7) * 16;
    int r0 = blockIdx.x * 32;
    const float* lg = logits + (size_t)(r0 + rl) * 128 + c0;
    const float* yt = ytrue  + (size_t)(r0 + rl) * 128 + c0;
    float*       pw = yp     + (size_t)(r0 + rl) * 128 + c0;
    float bs = 0.f, sp = 0.f, ss = 0.f, st = 0.f;
    #pragma unroll
    for (int q = 0; q < 4; ++q) {
        float4 l4 = *(const float4*)(lg + q * 4);
        float4 y4 = *(const float4*)(yt + q * 4);
        float4 w4 = *(const float4*)(cw + c0 + q * 4);
        float4 p4;
        p4.x = sigm(l4.x); p4.y = sigm(l4.y); p4.z = sigm(l4.z); p4.w = sigm(l4.w);
        *(float4*)(pw + q * 4) = p4;
        *(float4*)&Pl[rl * 128 + c0 + q * 4] = p4;
        *(float4*)&Tl[rl * 128 + c0 + q * 4] = y4;
        bs += w4.x * bce1(l4.x, y4.x) + w4.y * bce1(l4.y, y4.y)
            + w4.z * bce1(l4.z, y4.z) + w4.w * bce1(l4.w, y4.w);
        sp += p4.x + p4.y + p4.z + p4.w;
        ss += p4.x * p4.x + p4.y * p4.y + p4.z * p4.z + p4.w * p4.w;
        st += y4.x + y4.y + y4.z + y4.w;
    }
    #pragma unroll
    for (int o = 1; o < 8; o <<= 1) {
        sp += __shfl_xor(sp, o, 8);
        ss += __shfl_xor(ss, o, 8);
        st += __shfl_xor(st, o, 8);
    }
    float ls = 0.f;
    if ((t & 7) == 0) {
        sq[r0 + rl] = ss;
        float e = fmaxf(1.f + st - sp, 0.f);   // E1=1, E2=1
        ls = e * e;
    }
    bs = wave_red_sum(bs);
    ls = wave_red_sum(ls);
    if (lane == 0) { redb[w] = bs; reds[w] = ls; }
    __syncthreads();
    if (t == 0) {
        atomicAdd(&scal[0], redb[0] + redb[1] + redb[2] + redb[3]);
        atomicAdd(&scal[2], reds[0] + reds[1] + reds[2] + reds[3]);
    }
    if (t < 128) {
        float cp = 0.f;
        #pragma unroll 8
        for (int r = 0; r < 32; ++r) cp += Pl[r * 128 + t];
        atomicAdd(&colp[t], cp);
    } else {
        int c = t - 128;
        float ct = 0.f;
        #pragma unroll 8
        for (int r = 0; r < 32; ++r) ct += Tl[r * 128 + c];
        atomicAdd(&colt[c], ct);
    }
    // corr partial 8x8 tile per thread
    int tj = (t >> 4) * 8, tk = (t & 15) * 8;
    float acc[8][8];
    #pragma unroll
    for (int a = 0; a < 8; a++)
        #pragma unroll
        for (int b = 0; b < 8; b++) acc[a][b] = 0.f;
    for (int r = 0; r < 32; ++r) {
        float pj[8], pk[8], qj[8], qk[8];
        #pragma unroll
        for (int a = 0; a < 8; a++) { pj[a] = Pl[r * 128 + tj + a]; qj[a] = Tl[r * 128 + tj + a]; }
        #pragma unroll
        for (int b = 0; b < 8; b++) { pk[b] = Pl[r * 128 + tk + b]; qk[b] = Tl[r * 128 + tk + b]; }
        #pragma unroll
        for (int a = 0; a < 8; a++)
            #pragma unroll
            for (int b = 0; b < 8; b++)
                acc[a][b] += pj[a] * pk[b] - qj[a] * qk[b];
    }
    float* slice = cdp + (size_t)blockIdx.x * 16384;
    #pragma unroll
    for (int a = 0; a < 8; a++)
        #pragma unroll
        for (int b = 0; b < 8; b++)
            slice[(tj + a) * 128 + (tk + b)] = acc[a][b];
}

// slow path: exact dist2 for an off-diagonal masked pair (never taken in practice)
__device__ __attribute__((noinline)) float pair_dist2(const float* yp, const float* sq,
                                                      int gi, int gj)
{
    const float* a = yp + (size_t)gi * 128;
    const float* b = yp + (size_t)gj * 128;
    float d = 0.f;
    for (int t = 0; t < 128; ++t) d += a[t] * b[t];
    return sq[gi] + sq[gj] - 2.f * d;
}

// ---- K2: scaled-sim screen via fp8 MFMA. 256x128 tiles, 512 threads (8 waves
// of 64x64), BK=64, 48KB dbuf -> 3 blocks/CU. Paired-row LDS layout (R7):
// logical (row, chunk c) at line=row>>1, slot=(c|((row&1)<<2))^(line&7).
// Blocks 0..255 first reduce the corr partials (parallel shape: 64 entries x
// 8 slice-groups per block). Last-finished block assembles the outputs.
__global__ __launch_bounds__(512) void k_sim(const unsigned char* __restrict__ Fn8,
    const float* __restrict__ yp, const float* __restrict__ sq,
    const float* __restrict__ cdp, const float* __restrict__ colp,
    const float* __restrict__ colt, float* __restrict__ scal,
    float* __restrict__ out)
{
    __shared__ __align__(16) unsigned char As[2][16384];
    __shared__ __align__(16) unsigned char Bs[2][8192];
    __shared__ float fred[128];
    __shared__ float part[512];
    __shared__ int lastflag;
    int b = blockIdx.x;
    int t = threadIdx.x, lane = t & 63, w = t >> 6;
    int quad = lane >> 4, l15 = lane & 15;

    // corr reduction on blocks 0..255: 64 entries x 8 groups of 32 slices
    if (b < 256) {
        int e = b * 64 + (t & 63);
        int g0 = (t >> 6) * 32;
        float s = 0.f;
        #pragma unroll 8
        for (int sl = 0; sl < 32; ++sl)
            s += cdp[(size_t)(g0 + sl) * 16384 + e];
        part[t] = s;
        __syncthreads();
        if (t < 64) {
            float tot = 0.f;
            #pragma unroll
            for (int q = 0; q < 8; ++q) tot += part[q * 64 + t];
            float d = tot * (1.f / 8192.f);
            float v = wave_red_sum(d * d);
            if (t == 0) atomicAdd(&scal[3], v);
        }
        __syncthreads();
    }

    // decode tile: 8 XCDs x 132 contiguous; band bi (256 rows), col block jb
    int L = (b & 7) * 132 + (b >> 3);
    int bi = 0, rem = 64;
    while (L >= rem) { L -= rem; ++bi; rem -= 2; }
    int jb = 2 * bi + L;
    int row0 = bi * 256, col0 = jb * 128;
    int wr = (w >> 1) * 64, wc = (w & 1) * 64;

    // staging map: t -> line t>>3, slot t&7; u = slot^(line&7)
    int u_ = (t & 7) ^ ((t >> 3) & 7);
    int srow = (t >> 3) * 2 + (u_ >> 2);      // 0..127 (A) / 0..63 (B span)
    int schunk = u_ & 3;
    const unsigned char* gA = Fn8 + (size_t)(row0 + srow) * F_DIM + schunk * 16;
    const unsigned char* gB = Fn8 + (size_t)(col0 + srow) * F_DIM + schunk * 16;

    // read offsets: h = l15>>1, pp = (l15&1)<<2, q1 = (quad&1)*8, qh = quad>>1
    int h = l15 >> 1, pp = (l15 & 1) << 2, q1 = (quad & 1) * 8, qh = quad >> 1;
    int off0 = h * 128 + ((((0 + qh) | pp) ^ h) << 4) + q1;
    int off1 = h * 128 + ((((2 + qh) | pp) ^ h) << 4) + q1;

    f32x4 acc[4][4];
    #pragma unroll
    for (int i = 0; i < 4; i++)
        #pragma unroll
        for (int j2 = 0; j2 < 4; j2++) acc[i][j2] = (f32x4)0.f;

#define STAGE(K0, BUF) do {                                           \
        async16(gA + (K0),               &As[BUF][t * 16]);           \
        async16(gA + (K0) + 128 * F_DIM, &As[BUF][8192 + t * 16]);    \
        async16(gB + (K0),               &Bs[BUF][t * 16]);           \
    } while (0)

    STAGE(0, 0);
    for (int it = 0; it < 16; ++it) {
        int cur = it & 1;
        __syncthreads();                       // drains stage(it) into buf cur
        if (it + 1 < 16) STAGE((it + 1) * 64, 1 - cur);
        {
            long a0[4], b0[4];
            #pragma unroll
            for (int i = 0; i < 4; ++i) {
                a0[i] = *(const long*)&As[cur][wr * 64 + i * 1024 + off0];
                b0[i] = *(const long*)&Bs[cur][wc * 64 + i * 1024 + off0];
            }
            #pragma unroll
            for (int i = 0; i < 4; ++i)
                #pragma unroll
                for (int j2 = 0; j2 < 4; ++j2)
                    acc[i][j2] = __builtin_amdgcn_mfma_f32_16x16x32_fp8_fp8(
                        a0[i], b0[j2], acc[i][j2], 0, 0, 0);
        }
        {
            long a1[4], b1[4];
            #pragma unroll
            for (int i = 0; i < 4; ++i) {
                a1[i] = *(const long*)&As[cur][wr * 64 + i * 1024 + off1];
                b1[i] = *(const long*)&Bs[cur][wc * 64 + i * 1024 + off1];
            }
            #pragma unroll
            for (int i = 0; i < 4; ++i)
                #pragma unroll
                for (int j2 = 0; j2 < 4; ++j2)
                    acc[i][j2] = __builtin_amdgcn_mfma_f32_16x16x32_fp8_fp8(
                        a1[i], b1[j2], acc[i][j2], 0, 0, 0);
        }
    }
#undef STAGE

    float local = 0.f;
    for (int i = 0; i < 4; i++)
        for (int j2 = 0; j2 < 4; j2++)
            for (int r = 0; r < 4; r++) {
                float v = acc[i][j2][r];
                if (v > TAU_SCALED) {
                    int gi = row0 + wr + i * 16 + quad * 4 + r;  // C layout: row = quad*4+reg
                    int gj = col0 + wc + j2 * 16 + l15;          //           col = lane&15
                    if (gi < gj) local += 2.f * pair_dist2(yp, sq, gi, gj);
                    // gi == gj: dist2 exactly 0 — skip
                }
            }
    local = wave_red_sum(local);
    if (lane == 0) fred[w] = local;
    __syncthreads();
    if (t == 0) {
        float s8 = 0.f;
        #pragma unroll
        for (int q = 0; q < 8; ++q) s8 += fred[q];
        atomicAdd(&scal[1], s8);
        __threadfence();
        unsigned old = atomicAdd((unsigned int*)&scal[4], 1u);
        lastflag = (old == (unsigned)(NTILE - 1));
    }
    __syncthreads();
    if (!lastflag) return;

    // ---- finale: last block to finish assembles the outputs
    __threadfence();
    if (t < 128) {
        float Ej = colp[t] / 8192.f;
        float bp = colt[t];
        float bn = 8192.f - bp;
        float mint = 1.f + 0.2f * (bp / 8192.f);
        float moutt = 0.2f * ((8192.f - bp) / 8192.f);
        float pt = fmaxf(Ej - mint, 0.f);
        float nt = fmaxf(moutt - Ej, 0.f);
        fred[t] = bp * pt * pt + bn * nt * nt;
    }
    __syncthreads();
    if (t < 64) {
        float v = fred[t] + fred[t + 64];
        v = wave_red_sum(v);
        if (t == 0) {
            float lclass = v / 8192.f;
            float lbasis = scal[0] / (8192.f * 128.f);
            float lstt = atomicAdd(&scal[1], 0.f) / (8192.f * 8192.f);
            float lsample = scal[2] / 8192.f;
            float lcol = atomicAdd(&scal[3], 0.f) / 16384.f;
            float ltotal = lbasis + 0.3f * lstt + 0.3f * lclass + 0.5f * lsample + 0.3f * lcol;
            out[0] = ltotal; out[1] = lbasis; out[2] = lstt;
            out[3] = lclass; out[4] = lsample; out[5] = lcol;
        }
    }
}

extern "C" void kernel_launch(void* const* d_in, const int* in_sizes, int n_in,
                              void* d_out, int out_size, void* d_ws, size_t ws_size,
                              hipStream_t stream)
{
    const float* logits = (const float*)d_in[0];
    const float* ytrue  = (const float*)d_in[1];
    const float* feat   = (const float*)d_in[2];
    const float* cw     = (const float*)d_in[3];
    float* out = (float*)d_out;

    char* ws = (char*)d_ws;
    unsigned char* Fn8 = (unsigned char*)ws;                   // 8 MB fp8 f_norm (x16)
    float* yp   = (float*)(ws + (8u << 20));                   // 4 MB y_pred
    float* sq   = (float*)(ws + (12u << 20));                  // 32 KB row sums y_pred^2
    float* colp = (float*)(ws + (12u << 20) + 65536);          // 128 col sums pred
    float* colt = colp + 128;                                  // 128 col sums true
    float* scal = colp + 256;                                  // [0]=Lb [1]=Lstt [2]=Lsmp [3]=Lcol [4]=ctr
    float* cdp  = (float*)(ws + (13u << 20));                  // 256 x 64 KB corr partials

    hipMemsetAsync(colp, 0, 2048, stream);

    k_prep<<<2048, 256, 0, stream>>>(logits, ytrue, cw, feat, Fn8, yp, sq,
                                     colp, colt, scal, cdp);
    k_sim<<<NTILE, 512, 0, stream>>>(Fn8, yp, sq, cdp, colp, colt, scal, out);
}